// Round 5
// baseline (114.274 us; speedup 1.0000x reference)
//
#include <hip/hip_runtime.h>

// MedianPool2d 3x3, stride 1, reflect pad, [8,8,512,512] fp32.
// One wave spans a full 512-wide row (lane -> 8 cols), 8 output rows/thread,
// 4-slot rolling row buffer with 1-row prefetch. Halo columns via 2 scalar
// global loads per row (reflect-adjusted addresses for lanes 0/63) -- NO
// shuffles / ds ops, so the per-row stream is pure loads + min/max VALU.

#define MP_W 512
#define MP_H 512

typedef float floatx4 __attribute__((ext_vector_type(4)));

__device__ __forceinline__ void mnmx(float& a, float& b) {
    const float t = fminf(a, b);
    b = fmaxf(a, b);
    a = t;
}

__device__ __forceinline__ float med3f(float a, float b, float c) {
    return fmaxf(fminf(a, b), fminf(fmaxf(a, b), c));
}

__global__ __launch_bounds__(256) void median3x3_kernel(const float* __restrict__ x,
                                                        float* __restrict__ out) {
    const int tid  = blockIdx.x * 256 + threadIdx.x;
    const int lane = tid & 63;
    const int wv   = tid >> 6;     // 0..4095
    const int rg   = wv & 63;      // row group within image (8 rows each)
    const int bc   = wv >> 6;      // image 0..63
    const int y0   = rg << 3;
    const int x0   = lane << 3;

    // reflect-adjusted halo offsets (relative to rp = row base + x0):
    //   left  col x0-1  -> rp-1, except lane 0:  reflect -1 -> 1  => rp+1
    //   right col x0+8  -> rp+8, except lane 63: reflect 512->510 => rp+6
    const int off_l = (lane == 0)  ? 1 : -1;
    const int off_r = (lane == 63) ? 6 : 8;

    const float* base  = x   + ((size_t)bc << 18);
    float*       obase = out + ((size_t)bc << 18) + (size_t)y0 * MP_W + x0;

    auto row_ptr = [&](int yy) -> const float* {
        yy = (yy < 0) ? -yy : (yy >= MP_H ? 2 * MP_H - 2 - yy : yy);  // reflect
        return base + (size_t)yy * MP_W + x0;
    };

    floatx4 bufA[4], bufB[4];   // cols x0..x0+3, x0+4..x0+7
    float   bufL[4], bufR[4];   // halo cols x0-1, x0+8 (reflected at edges)

    #pragma unroll
    for (int k = 0; k < 3; ++k) {
        const float* rp = row_ptr(y0 - 1 + k);
        bufA[k] = *(const floatx4*)rp;
        bufB[k] = *(const floatx4*)(rp + 4);
        bufL[k] = rp[off_l];
        bufR[k] = rp[off_r];
    }

    #pragma unroll
    for (int r = 0; r < 8; ++r) {
        // prefetch row y0+r+2 into the free slot (pure loads, no dependent ops)
        if (r < 7) {
            const int s = (r + 3) & 3;
            const float* rp = row_ptr(y0 + r + 2);
            bufA[s] = *(const floatx4*)rp;
            bufB[s] = *(const floatx4*)(rp + 4);
            bufL[s] = rp[off_l];
            bufR[s] = rp[off_r];
        }

        // gather the 3 rows of the window for this output row
        float v[3][10];
        #pragma unroll
        for (int k = 0; k < 3; ++k) {
            const int s = (r + k) & 3;
            const floatx4 a = bufA[s];
            const floatx4 b = bufB[s];
            v[k][0] = bufL[s];
            v[k][1] = a.x; v[k][2] = a.y; v[k][3] = a.z; v[k][4] = a.w;
            v[k][5] = b.x; v[k][6] = b.y; v[k][7] = b.z; v[k][8] = b.w;
            v[k][9] = bufR[s];
        }

        // sort each vertical column triple (shared by 3 horizontal windows)
        float lo[10], mi[10], hi[10];
        #pragma unroll
        for (int j = 0; j < 10; ++j) {
            float a = v[0][j], b = v[1][j], c = v[2][j];
            mnmx(a, b); mnmx(a, c); mnmx(b, c);
            lo[j] = a; mi[j] = b; hi[j] = c;
        }

        float res[8];
        #pragma unroll
        for (int j = 0; j < 8; ++j) {
            const float L = fmaxf(fmaxf(lo[j], lo[j + 1]), lo[j + 2]);
            const float M = med3f(mi[j], mi[j + 1], mi[j + 2]);
            const float H = fminf(fminf(hi[j], hi[j + 1]), hi[j + 2]);
            res[j] = med3f(L, M, H);
        }

        float* op = obase + (size_t)r * MP_W;
        floatx4 o1 = {res[0], res[1], res[2], res[3]};
        floatx4 o2 = {res[4], res[5], res[6], res[7]};
        __builtin_nontemporal_store(o1, (floatx4*)op);
        __builtin_nontemporal_store(o2, (floatx4*)(op + 4));
    }
}

extern "C" void kernel_launch(void* const* d_in, const int* in_sizes, int n_in,
                              void* d_out, int out_size, void* d_ws, size_t ws_size,
                              hipStream_t stream) {
    const float* x = (const float*)d_in[0];
    float* out = (float*)d_out;
    // 64 outputs per thread -> 262144 threads -> 1024 blocks of 256
    const int n_threads = out_size / 64;
    const int block = 256;
    const int grid = n_threads / block;
    median3x3_kernel<<<grid, block, 0, stream>>>(x, out);
}

// Round 6
// 108.813 us; speedup vs baseline: 1.0502x; 1.0502x over previous
//
#include <hip/hip_runtime.h>

// MedianPool2d 3x3, stride 1, reflect pad, [8,8,512,512] fp32.
// Dense-coalesced variant: lane i owns 4 cols (16 B) at lane-stride 16 B, so
// every global dwordx4 load/store is a fully-dense 1 KB wave transaction
// (8 x 128 B lines, no half-used lines). A wave spans half a row (256 cols);
// 8 output rows per thread with a 4-slot rolling row buffer (1-row prefetch).
// Halo columns via 2 scalar L1-hit loads per row. 2048 blocks -> 8 blocks/CU.

#define MP_W 512
#define MP_H 512

typedef float floatx4 __attribute__((ext_vector_type(4)));

__device__ __forceinline__ void mnmx(float& a, float& b) {
    const float t = fminf(a, b);
    b = fmaxf(a, b);
    a = t;
}

__device__ __forceinline__ float med3f(float a, float b, float c) {
    return fmaxf(fminf(a, b), fminf(fmaxf(a, b), c));
}

__global__ __launch_bounds__(256) void median3x3_kernel(const float* __restrict__ x,
                                                        float* __restrict__ out) {
    const int tid  = blockIdx.x * 256 + threadIdx.x;
    const int lane = tid & 63;
    const int wv   = tid >> 6;        // 0..8191
    const int hf   = wv & 1;          // which 256-col half of the row
    const int rg   = (wv >> 1) & 63;  // 8-row group within image
    const int bc   = wv >> 7;         // image 0..63
    const int y0   = rg << 3;
    const int x0   = (hf << 8) + (lane << 2);   // dense: lane-stride 16 B

    // halo offsets relative to rp = row base + x0:
    //   left  col x0-1 -> rp[-1]; x0==0  reflects -1 -> 1   => rp[1]
    //   right col x0+4 -> rp[4];  x0==508 reflects 512 -> 510 => rp[2]
    const int off_l = (x0 == 0)          ? 1 : -1;
    const int off_r = (x0 == MP_W - 4)   ? 2 : 4;

    const float* base  = x   + ((size_t)bc << 18);
    float*       obase = out + ((size_t)bc << 18) + (size_t)y0 * MP_W + x0;

    auto row_ptr = [&](int yy) -> const float* {
        yy = (yy < 0) ? -yy : (yy >= MP_H ? 2 * MP_H - 2 - yy : yy);  // reflect
        return base + (size_t)yy * MP_W + x0;
    };

    floatx4 bufV[4];            // cols x0..x0+3
    float   bufL[4], bufR[4];   // halo cols x0-1, x0+4 (reflect-adjusted)

    #pragma unroll
    for (int k = 0; k < 3; ++k) {
        const float* rp = row_ptr(y0 - 1 + k);
        bufV[k] = *(const floatx4*)rp;
        bufL[k] = rp[off_l];
        bufR[k] = rp[off_r];
    }

    #pragma unroll
    for (int r = 0; r < 8; ++r) {
        // prefetch row y0+r+2 into the free slot (pure loads)
        if (r < 7) {
            const int s = (r + 3) & 3;
            const float* rp = row_ptr(y0 + r + 2);
            bufV[s] = *(const floatx4*)rp;
            bufL[s] = rp[off_l];
            bufR[s] = rp[off_r];
        }

        // window rows for this output row: columns x0-1 .. x0+4
        float v[3][6];
        #pragma unroll
        for (int k = 0; k < 3; ++k) {
            const int s = (r + k) & 3;
            const floatx4 a = bufV[s];
            v[k][0] = bufL[s];
            v[k][1] = a.x; v[k][2] = a.y; v[k][3] = a.z; v[k][4] = a.w;
            v[k][5] = bufR[s];
        }

        // sort each vertical column triple (shared by the 3 horizontal windows)
        float lo[6], mi[6], hi[6];
        #pragma unroll
        for (int j = 0; j < 6; ++j) {
            float a = v[0][j], b = v[1][j], c = v[2][j];
            mnmx(a, b); mnmx(a, c); mnmx(b, c);
            lo[j] = a; mi[j] = b; hi[j] = c;
        }

        float res[4];
        #pragma unroll
        for (int j = 0; j < 4; ++j) {
            const float L = fmaxf(fmaxf(lo[j], lo[j + 1]), lo[j + 2]);
            const float M = med3f(mi[j], mi[j + 1], mi[j + 2]);
            const float H = fminf(fminf(hi[j], hi[j + 1]), hi[j + 2]);
            res[j] = med3f(L, M, H);
        }

        floatx4 o = {res[0], res[1], res[2], res[3]};
        __builtin_nontemporal_store(o, (floatx4*)(obase + (size_t)r * MP_W));
    }
}

extern "C" void kernel_launch(void* const* d_in, const int* in_sizes, int n_in,
                              void* d_out, int out_size, void* d_ws, size_t ws_size,
                              hipStream_t stream) {
    const float* x = (const float*)d_in[0];
    float* out = (float*)d_out;
    // 32 outputs per thread (4 cols x 8 rows) -> 524288 threads -> 2048 blocks
    const int n_threads = out_size / 32;
    const int block = 256;
    const int grid = n_threads / block;   // 2048
    median3x3_kernel<<<grid, block, 0, stream>>>(x, out);
}